// Round 9
// baseline (231.060 us; speedup 1.0000x reference)
//
#include <hip/hip_runtime.h>

// Problem constants
#define EMB  4096
#define DH   128      // QKV_DIM
#define NH   32       // N_HEADS
#define NTOK 16384    // B*S
#define NCOL 384      // qs | k | v columns

// GEMM tile: 64(M) x 384(N=all) block, BK=64, 6 waves, wave tile 64x64 (acc 4x4)
#define BM 64
#define BK 64

typedef __attribute__((ext_vector_type(8))) short short8;
typedef __attribute__((ext_vector_type(4))) short short4_t;
typedef __attribute__((ext_vector_type(4))) float f32x4;

// f32 pair -> packed bf16x2, RNE (hardware cvt)
static __device__ __forceinline__ unsigned int cvt2(float a, float b) {
    unsigned int r;
    asm volatile("v_cvt_pk_bf16_f32 %0, %1, %2" : "=v"(r) : "v"(a), "v"(b));
    return r;
}
// scalar f32 -> bf16 bits, RNE (prep_w only)
static __device__ __forceinline__ unsigned short f2bf(float f) {
    unsigned int u = __builtin_bit_cast(unsigned int, f);
    u += 0x7fffu + ((u >> 16) & 1u);
    return (unsigned short)(u >> 16);
}
// async global->LDS, 16B per lane; LDS dest = wave-uniform base + lane*16
static __device__ __forceinline__ void gload_lds16(const void* g, void* l) {
    __builtin_amdgcn_global_load_lds(
        (const __attribute__((address_space(1))) unsigned int*)g,
        (__attribute__((address_space(3))) unsigned int*)l, 16, 0, 0);
}

// ---------------------------------------------------------------------------
// Kernel 1: build W3B — combined weights W3[384][4096] (bf16), stored as
// 64x64 tiles in gload_lds-linear order with the XOR-chunk swizzle
// PRE-APPLIED, so GEMM B-staging is 8 contiguous 1-KB reads per tile.
//   byte(n,D) = p*524288 + kt*8192 + (r>>3)*1024 + l*16 + (D&7)*2
//   where p=n>>6, r=n&63, kt=D>>6, c_src=(D>>3)&7, l=(r&7)*8 + (c_src^(r&7)).
// Also bias[384].
// ---------------------------------------------------------------------------
__global__ void prep_w(const float* __restrict__ Wq, const float* __restrict__ bq,
                       const float* __restrict__ Wk, const float* __restrict__ bk,
                       const float* __restrict__ Wv, const float* __restrict__ bv,
                       unsigned short* __restrict__ W3B, float* __restrict__ bias) {
    const int tid = blockIdx.x * 256 + threadIdx.x;   // [0, 384*512)
    const int n  = tid >> 9;          // output column [0,384)
    const int ck = tid & 511;         // 8-element chunk of the 4096 K dim
    const int D0 = ck * 8;

    float v[8];
    if (n < DH) {
#pragma unroll
        for (int e = 0; e < 8; ++e) {
            const float4* p = (const float4*)(Wq + (size_t)(D0 + e) * (DH * NH) + n * NH);
            float s = 0.f;
#pragma unroll
            for (int i = 0; i < 8; ++i) { float4 q = p[i]; s += (q.x + q.y) + (q.z + q.w); }
            v[e] = s;
        }
    } else if (n < 2 * DH) {
#pragma unroll
        for (int e = 0; e < 8; ++e) v[e] = Wk[(size_t)(D0 + e) * DH + (n - DH)];
    } else {
#pragma unroll
        for (int e = 0; e < 8; ++e) v[e] = Wv[(size_t)(D0 + e) * DH + (n - 2 * DH)];
    }

    union { short8 s; unsigned int u[4]; } pk;
#pragma unroll
    for (int j = 0; j < 4; ++j)
        pk.u[j] = (unsigned int)f2bf(v[2 * j]) | ((unsigned int)f2bf(v[2 * j + 1]) << 16);

    const int p  = n >> 6, r = n & 63;
    const int kt = ck >> 3, cs = ck & 7;
    const int l  = ((r & 7) << 3) | (cs ^ (r & 7));
    char* dst = (char*)W3B + (size_t)p * 524288 + (size_t)kt * 8192 + (r >> 3) * 1024 + l * 16;
    *(short8*)dst = pk.s;

    if (ck == 0) {
        float b;
        if (n < DH) {
            float s = 0.f;
#pragma unroll
            for (int h = 0; h < NH; ++h) s += bq[n * NH + h];
            b = s;
        } else if (n < 2 * DH) {
            b = bk[n - DH];
        } else {
            b = bv[n - 2 * DH];
        }
        bias[n] = b;
    }
}

// ---------------------------------------------------------------------------
// Kernel 2: qkv_partial[ks][m0..m0+64][0..384] = x[stripe, ks-half] @ W3.
// BN = 384: each block computes ALL output columns for its 64-row stripe, so
// every X element is fetched from HBM exactly once (was 3x), and each wave
// owns one 64-col W3B panel (1.5 MB/half -> L2-resident).
// 6 waves (384 thr), 56 KB LDS, 2 blocks/CU. Single-buffered 2-phase loop
// (R6 structure). Swizzle: 16B chunk c of row r lives at LDS chunk c^(r&7).
// ---------------------------------------------------------------------------
__global__ __launch_bounds__(384) void gemm_qkv(const float* __restrict__ X,
                         const unsigned short* __restrict__ W3B,
                         float* __restrict__ qkvp, int nsplit) {
    __shared__ __align__(16) unsigned short Asm[BM * BK];        //  8 KB
    __shared__ __align__(16) unsigned short Bsm[6 * 64 * BK];    // 48 KB

    // XCD-bijective remap over 256*nsplit blocks (divisible by 8)
    const int nblk  = 256 * nsplit;
    const int chnk  = nblk >> 3;
    const int bid   = blockIdx.x;
    const int wkid  = (bid & 7) * chnk + (bid >> 3);
    const int ks    = wkid >> 8;              // [0, nsplit)
    const int my    = wkid & 255;
    const int m0    = my * BM;
    const int klen  = EMB / nsplit;
    const int koff  = ks * klen;
    const int nt    = klen / BK;

    const int t = threadIdx.x, lane = t & 63, w = t >> 6;   // w in {0..5}
    const int lmod = lane & 15, lgrp = lane >> 4;

    f32x4 acc[4][4] = {};

    // A staging (waves 0-3 only): wave w covers rows [w*16, w*16+16);
    // instr i covers rows w*16 + i*4 + (lane>>4), 16 B at (lane&15)*16.
    const int arow4 = lane >> 4;
    const float* xp = X + (size_t)(m0 + w * 16 + arow4) * EMB + koff + (lane & 15) * 4;
    const int acs = (lane & 15) >> 1;
    const int ah4 = (lane & 1) * 4;

    // B staging (all 6 waves): wave w stages + consumes panel w.
    const char* wsrc = (const char*)W3B + (size_t)w * 524288 + ((size_t)koff >> 6) * 8192 + lane * 16;
    unsigned short* bdst = &Bsm[w * 4096];

    float4 av[4];

#define LOAD_AV(T) do { \
    _Pragma("unroll") \
    for (int i = 0; i < 4; ++i) av[i] = *(const float4*)(xp + (T) * BK + i * 4 * EMB); \
} while (0)

#define STAGE_B(T) do { \
    const char* bs = wsrc + (size_t)(T) * 8192; \
    _Pragma("unroll") \
    for (int i8 = 0; i8 < 8; ++i8) gload_lds16(bs + i8 * 1024, bdst + i8 * 8 * BK); \
} while (0)

#define WRITE_A() do { \
    _Pragma("unroll") \
    for (int idx = 0; idx < 4; ++idx) { \
        const int rl = w * 16 + idx * 4 + arow4; \
        union { short4_t s; unsigned int u[2]; } pk; \
        pk.u[0] = cvt2(av[idx].x, av[idx].y); \
        pk.u[1] = cvt2(av[idx].z, av[idx].w); \
        *(short4_t*)(&Asm[rl * BK + ((acs ^ (rl & 7)) << 3) + ah4]) = pk.s; \
    } \
} while (0)

    // prologue: A regs for tile 0
    if (w < 4) LOAD_AV(0);

    for (int tt = 0; tt < nt; ++tt) {
        __syncthreads();                      // readers of previous tile done
        if (w < 4) WRITE_A();                 // auto vmcnt-wait on av
        STAGE_B(tt);
        asm volatile("s_waitcnt vmcnt(0)" ::: "memory");
        __syncthreads();                      // tile resident
        if (w < 4 && tt + 1 < nt) LOAD_AV(tt + 1);  // HBM latency hides under MFMA

#pragma unroll
        for (int kh = 0; kh < 2; ++kh) {
            const int cs = ((kh * 4 + lgrp) ^ (lmod & 7)) * 8;
            short8 af[4], bf[4];
#pragma unroll
            for (int i = 0; i < 4; ++i)
                af[i] = *(const short8*)(&Asm[(i * 16 + lmod) * BK + cs]);
#pragma unroll
            for (int j = 0; j < 4; ++j)
                bf[j] = *(const short8*)(&Bsm[w * 4096 + (j * 16 + lmod) * BK + cs]);
#pragma unroll
            for (int i = 0; i < 4; ++i)
#pragma unroll
                for (int j = 0; j < 4; ++j)
                    acc[i][j] = __builtin_amdgcn_mfma_f32_16x16x32_bf16(af[i], bf[j], acc[i][j], 0, 0, 0);
        }
    }

    // epilogue: C/D layout col = lane&15, row = (lane>>4)*4 + reg
    float* outp = qkvp + (size_t)ks * NTOK * NCOL;
#pragma unroll
    for (int j = 0; j < 4; ++j) {
        const int gcol = w * 64 + j * 16 + lmod;
#pragma unroll
        for (int i = 0; i < 4; ++i) {
            const int grow = m0 + i * 16 + (lgrp << 2);
#pragma unroll
            for (int r = 0; r < 4; ++r)
                outp[(size_t)(grow + r) * NCOL + gcol] = acc[i][j][r];
        }
    }
#undef LOAD_AV
#undef STAGE_B
#undef WRITE_A
}

// ---------------------------------------------------------------------------
// Kernel 3: sum split-K partials + bias, per-token rank-1 softmax, broadcast.
// One wave per token, 4 tokens per block.
// ---------------------------------------------------------------------------
__global__ void attn_out(const float* __restrict__ qkv0, const float* __restrict__ qkv1,
                         const float* __restrict__ bias, float* __restrict__ out,
                         int nsplit) {
    __shared__ float kvs[4][DH][2];
    __shared__ float osm[4][DH];
    const int t = threadIdx.x, lane = t & 63, w = t >> 6;
    const int token = blockIdx.x * 4 + w;
    const float* b0 = qkv0 + (size_t)token * NCOL;

    float q0  = b0[lane],       q1  = b0[64 + lane];
    float kk0 = b0[128 + lane], kk1 = b0[192 + lane];
    float vv0 = b0[256 + lane], vv1 = b0[320 + lane];
    if (nsplit == 2) {
        const float* b1 = qkv1 + (size_t)token * NCOL;
        q0  += b1[lane];       q1  += b1[64 + lane];
        kk0 += b1[128 + lane]; kk1 += b1[192 + lane];
        vv0 += b1[256 + lane]; vv1 += b1[320 + lane];
    }
    q0  += bias[lane];       q1  += bias[64 + lane];
    kk0 += bias[128 + lane]; kk1 += bias[192 + lane];
    vv0 += bias[256 + lane]; vv1 += bias[320 + lane];

    kvs[w][lane][0]      = kk0;  kvs[w][lane][1]      = vv0;
    kvs[w][64 + lane][0] = kk1;  kvs[w][64 + lane][1] = vv1;

    float lmax = fmaxf(kk0, kk1), lmin = fminf(kk0, kk1);
#pragma unroll
    for (int off = 32; off; off >>= 1) {
        lmax = fmaxf(lmax, __shfl_xor(lmax, off));
        lmin = fminf(lmin, __shfl_xor(lmin, off));
    }
    __syncthreads();

    const float c  = 0.088388347648318447f * 1.4426950408889634f; // scale * log2(e)
    const float a0 = q0 * c, a1 = q1 * c;
    const float m0 = (a0 >= 0.f) ? a0 * lmax : a0 * lmin;
    const float m1 = (a1 >= 0.f) ? a1 * lmax : a1 * lmin;

    float s00 = 0.f, s01 = 0.f, s10 = 0.f, s11 = 0.f;
#pragma unroll 4
    for (int e = 0; e < DH; ++e) {
        const float2 kv = *(const float2*)&kvs[w][e][0];   // broadcast read
        const float p0 = exp2f(fmaf(a0, kv.x, -m0));
        const float p1 = exp2f(fmaf(a1, kv.x, -m1));
        s00 += p0;  s01 = fmaf(p0, kv.y, s01);
        s10 += p1;  s11 = fmaf(p1, kv.y, s11);
    }
    osm[w][lane]      = s01 / s00;
    osm[w][64 + lane] = s11 / s10;
    __syncthreads();

    float* orow = out + (size_t)token * (DH * NH);
#pragma unroll
    for (int it = 0; it < 16; ++it) {
        const int idx = it * 64 + lane;          // float4 index within the 4096-row
        const float val = osm[w][idx >> 3];      // d = (idx*4)/32
        float4 f4; f4.x = val; f4.y = val; f4.z = val; f4.w = val;
        *(float4*)(orow + idx * 4) = f4;
    }
}

// ---------------------------------------------------------------------------
extern "C" void kernel_launch(void* const* d_in, const int* in_sizes, int n_in,
                              void* d_out, int out_size, void* d_ws, size_t ws_size,
                              hipStream_t stream) {
    const float* x  = (const float*)d_in[0];
    const float* Wq = (const float*)d_in[1];
    const float* bq = (const float*)d_in[2];
    const float* Wk = (const float*)d_in[3];
    const float* bk = (const float*)d_in[4];
    const float* Wv = (const float*)d_in[5];
    const float* bv = (const float*)d_in[6];
    float* out = (float*)d_out;

    char* ws = (char*)d_ws;
    const size_t off_bias = 3145728;                 // W3B: 6*524288
    const size_t off_q0   = off_bias + 4096;
    const size_t off_q1   = off_q0 + (size_t)NTOK * NCOL * 4;
    const size_t need2    = off_q1 + (size_t)NTOK * NCOL * 4;  // 53,481,472 B

    unsigned short* W3B = (unsigned short*)ws;
    float* bias = (float*)(ws + off_bias);
    float* qkv0 = (float*)(ws + off_q0);
    const int nsplit = (ws_size >= need2) ? 2 : 1;
    float* qkv1 = (nsplit == 2) ? (float*)(ws + off_q1) : qkv0;

    prep_w<<<(NCOL * 512) / 256, 256, 0, stream>>>(Wq, bq, Wk, bk, Wv, bv, W3B, bias);
    gemm_qkv<<<256 * nsplit, 384, 0, stream>>>(x, W3B, qkv0, nsplit);
    attn_out<<<NTOK / 4, 256, 0, stream>>>(qkv0, qkv1, bias, out, nsplit);
}

// Round 10
// 215.070 us; speedup vs baseline: 1.0743x; 1.0743x over previous
//
#include <hip/hip_runtime.h>

// Problem constants
#define EMB  4096
#define DH   128      // QKV_DIM
#define NH   32       // N_HEADS
#define NTOK 16384    // B*S
#define NCOL 384      // qs | k | v columns

// GEMM tile: 64(M) x 384(N=all) block, BK=64, 6 waves, wave tile 64x64 (acc 4x4)
#define BM 64
#define BK 64

typedef __attribute__((ext_vector_type(8))) short short8;
typedef __attribute__((ext_vector_type(4))) short short4_t;
typedef __attribute__((ext_vector_type(4))) float f32x4;

// f32 pair -> packed bf16x2, RNE (hardware cvt)
static __device__ __forceinline__ unsigned int cvt2(float a, float b) {
    unsigned int r;
    asm volatile("v_cvt_pk_bf16_f32 %0, %1, %2" : "=v"(r) : "v"(a), "v"(b));
    return r;
}
// scalar f32 -> bf16 bits, RNE (prep_w only)
static __device__ __forceinline__ unsigned short f2bf(float f) {
    unsigned int u = __builtin_bit_cast(unsigned int, f);
    u += 0x7fffu + ((u >> 16) & 1u);
    return (unsigned short)(u >> 16);
}

// ---------------------------------------------------------------------------
// Kernel 1: build W3F — combined weights W3[384][4096] (bf16) in MFMA
// FRAGMENT-LINEAR order: for panel p (=n>>6), k-tile kt (=D>>6), chunk
// (kh*4+j), lane (lgrp*16+lmod), the 16 B at
//   byte = p*524288 + kt*8192 + (kh*4+j)*1024 + lane*16
// hold B[n = j*16+lmod][D = kt*64 + kh*32 + lgrp*8 + e], e=0..7 — i.e. exactly
// one lane's bf-operand fragment. GEMM B-loads become coalesced 1-KB dwordx4
// straight into VGPRs (no LDS). Also bias[384].
// ---------------------------------------------------------------------------
__global__ void prep_w(const float* __restrict__ Wq, const float* __restrict__ bq,
                       const float* __restrict__ Wk, const float* __restrict__ bk,
                       const float* __restrict__ Wv, const float* __restrict__ bv,
                       unsigned short* __restrict__ W3F, float* __restrict__ bias) {
    const int tid = blockIdx.x * 256 + threadIdx.x;   // [0, 384*512)
    const int n  = tid >> 9;          // output column [0,384)
    const int ck = tid & 511;         // 8-element chunk of the 4096 K dim
    const int D0 = ck * 8;

    float v[8];
    if (n < DH) {
#pragma unroll
        for (int e = 0; e < 8; ++e) {
            const float4* p = (const float4*)(Wq + (size_t)(D0 + e) * (DH * NH) + n * NH);
            float s = 0.f;
#pragma unroll
            for (int i = 0; i < 8; ++i) { float4 q = p[i]; s += (q.x + q.y) + (q.z + q.w); }
            v[e] = s;
        }
    } else if (n < 2 * DH) {
#pragma unroll
        for (int e = 0; e < 8; ++e) v[e] = Wk[(size_t)(D0 + e) * DH + (n - DH)];
    } else {
#pragma unroll
        for (int e = 0; e < 8; ++e) v[e] = Wv[(size_t)(D0 + e) * DH + (n - 2 * DH)];
    }

    union { short8 s; unsigned int u[4]; } pk;
#pragma unroll
    for (int j = 0; j < 4; ++j)
        pk.u[j] = (unsigned int)f2bf(v[2 * j]) | ((unsigned int)f2bf(v[2 * j + 1]) << 16);

    // fragment-linear address
    const int p    = n >> 6, r = n & 63;
    const int jfr  = r >> 4, lmod = r & 15;
    const int kt   = ck >> 3;
    const int kh   = (ck >> 2) & 1;
    const int lgrp = ck & 3;
    const int lane = lgrp * 16 + lmod;
    char* dst = (char*)W3F + (size_t)p * 524288 + (size_t)kt * 8192
              + (kh * 4 + jfr) * 1024 + lane * 16;
    *(short8*)dst = pk.s;

    if (ck == 0) {
        float b;
        if (n < DH) {
            float s = 0.f;
#pragma unroll
            for (int h = 0; h < NH; ++h) s += bq[n * NH + h];
            b = s;
        } else if (n < 2 * DH) {
            b = bk[n - DH];
        } else {
            b = bv[n - 2 * DH];
        }
        bias[n] = b;
    }
}

// ---------------------------------------------------------------------------
// Kernel 2: qkv_partial[ks][m0..m0+64][0..384] = x[stripe, ks-half] @ W3.
// B is loaded global->VGPR directly from the fragment-linear W3F (L2-resident,
// 8 coalesced 1-KB dwordx4 per wave-iter) — no B LDS, no gload_lds, no
// vmcnt(0) drain. LDS holds only the shared 8-KB A tile (all 6 waves read it).
// 6 waves (384 thr), split-K=2 -> 512 blocks (2/CU, 12 waves/CU).
// A swizzle: 16B chunk c of row r lives at LDS chunk c^(r&7)  (proven R6-R9).
// ---------------------------------------------------------------------------
__global__ __launch_bounds__(384) void gemm_qkv(const float* __restrict__ X,
                         const unsigned short* __restrict__ W3F,
                         float* __restrict__ qkvp, int nsplit) {
    __shared__ __align__(16) unsigned short Asm[BM * BK];        // 8 KB

    // XCD-bijective remap over 256*nsplit blocks (divisible by 8)
    const int nblk  = 256 * nsplit;
    const int chnk  = nblk >> 3;
    const int bid   = blockIdx.x;
    const int wkid  = (bid & 7) * chnk + (bid >> 3);
    const int ks    = wkid >> 8;              // [0, nsplit)
    const int my    = wkid & 255;
    const int m0    = my * BM;
    const int klen  = EMB / nsplit;
    const int koff  = ks * klen;
    const int nt    = klen / BK;

    const int t = threadIdx.x, lane = t & 63, w = t >> 6;   // w in {0..5}
    const int lmod = lane & 15, lgrp = lane >> 4;

    f32x4 acc[4][4] = {};

    // A staging (waves 0-3): wave w covers rows [w*16, w*16+16);
    // instr i covers rows w*16 + i*4 + (lane>>4), 16 B at (lane&15)*16.
    const int arow4 = lane >> 4;
    const float* xp = X + (size_t)(m0 + w * 16 + arow4) * EMB + koff + (lane & 15) * 4;
    const int acs = (lane & 15) >> 1;
    const int ah4 = (lane & 1) * 4;

    // B source: wave w consumes panel w, fragment-linear
    const char* bsrc = (const char*)W3F + (size_t)w * 524288
                     + ((size_t)koff >> 6) * 8192 + lane * 16;

    float4 av[4];

#define LOAD_AV(T) do { \
    _Pragma("unroll") \
    for (int i = 0; i < 4; ++i) av[i] = *(const float4*)(xp + (T) * BK + i * 4 * EMB); \
} while (0)

#define WRITE_A() do { \
    _Pragma("unroll") \
    for (int idx = 0; idx < 4; ++idx) { \
        const int rl = w * 16 + idx * 4 + arow4; \
        union { short4_t s; unsigned int u[2]; } pk; \
        pk.u[0] = cvt2(av[idx].x, av[idx].y); \
        pk.u[1] = cvt2(av[idx].z, av[idx].w); \
        *(short4_t*)(&Asm[rl * BK + ((acs ^ (rl & 7)) << 3) + ah4]) = pk.s; \
    } \
} while (0)

    // prologue: A regs for tile 0
    if (w < 4) LOAD_AV(0);

    for (int tt = 0; tt < nt; ++tt) {
        __syncthreads();                      // readers of previous tile done
        if (w < 4) WRITE_A();                 // av(tile tt); auto vmcnt-wait
        __syncthreads();                      // tile resident
        if (w < 4 && tt + 1 < nt) LOAD_AV(tt + 1);  // streams under compute

        const char* bt = bsrc + (size_t)tt * 8192;
#pragma unroll
        for (int kh = 0; kh < 2; ++kh) {
            short8 af[4], bf[4];
#pragma unroll
            for (int j = 0; j < 4; ++j)
                bf[j] = *(const short8*)(bt + (kh * 4 + j) * 1024);   // global, L2
            const int cs = ((kh * 4 + lgrp) ^ (lmod & 7)) * 8;
#pragma unroll
            for (int i = 0; i < 4; ++i)
                af[i] = *(const short8*)(&Asm[(i * 16 + lmod) * BK + cs]);
#pragma unroll
            for (int i = 0; i < 4; ++i)
#pragma unroll
                for (int j = 0; j < 4; ++j)
                    acc[i][j] = __builtin_amdgcn_mfma_f32_16x16x32_bf16(af[i], bf[j], acc[i][j], 0, 0, 0);
        }
    }

    // epilogue: C/D layout col = lane&15, row = (lane>>4)*4 + reg
    float* outp = qkvp + (size_t)ks * NTOK * NCOL;
#pragma unroll
    for (int j = 0; j < 4; ++j) {
        const int gcol = w * 64 + j * 16 + lmod;
#pragma unroll
        for (int i = 0; i < 4; ++i) {
            const int grow = m0 + i * 16 + (lgrp << 2);
#pragma unroll
            for (int r = 0; r < 4; ++r)
                outp[(size_t)(grow + r) * NCOL + gcol] = acc[i][j][r];
        }
    }
#undef LOAD_AV
#undef WRITE_A
}

// ---------------------------------------------------------------------------
// Kernel 3: sum split-K partials + bias, per-token rank-1 softmax, broadcast.
// One wave per token, 4 tokens per block.
// ---------------------------------------------------------------------------
__global__ void attn_out(const float* __restrict__ qkv0, const float* __restrict__ qkv1,
                         const float* __restrict__ bias, float* __restrict__ out,
                         int nsplit) {
    __shared__ float kvs[4][DH][2];
    __shared__ float osm[4][DH];
    const int t = threadIdx.x, lane = t & 63, w = t >> 6;
    const int token = blockIdx.x * 4 + w;
    const float* b0 = qkv0 + (size_t)token * NCOL;

    float q0  = b0[lane],       q1  = b0[64 + lane];
    float kk0 = b0[128 + lane], kk1 = b0[192 + lane];
    float vv0 = b0[256 + lane], vv1 = b0[320 + lane];
    if (nsplit == 2) {
        const float* b1 = qkv1 + (size_t)token * NCOL;
        q0  += b1[lane];       q1  += b1[64 + lane];
        kk0 += b1[128 + lane]; kk1 += b1[192 + lane];
        vv0 += b1[256 + lane]; vv1 += b1[320 + lane];
    }
    q0  += bias[lane];       q1  += bias[64 + lane];
    kk0 += bias[128 + lane]; kk1 += bias[192 + lane];
    vv0 += bias[256 + lane]; vv1 += bias[320 + lane];

    kvs[w][lane][0]      = kk0;  kvs[w][lane][1]      = vv0;
    kvs[w][64 + lane][0] = kk1;  kvs[w][64 + lane][1] = vv1;

    float lmax = fmaxf(kk0, kk1), lmin = fminf(kk0, kk1);
#pragma unroll
    for (int off = 32; off; off >>= 1) {
        lmax = fmaxf(lmax, __shfl_xor(lmax, off));
        lmin = fminf(lmin, __shfl_xor(lmin, off));
    }
    __syncthreads();

    const float c  = 0.088388347648318447f * 1.4426950408889634f; // scale * log2(e)
    const float a0 = q0 * c, a1 = q1 * c;
    const float m0 = (a0 >= 0.f) ? a0 * lmax : a0 * lmin;
    const float m1 = (a1 >= 0.f) ? a1 * lmax : a1 * lmin;

    float s00 = 0.f, s01 = 0.f, s10 = 0.f, s11 = 0.f;
#pragma unroll 4
    for (int e = 0; e < DH; ++e) {
        const float2 kv = *(const float2*)&kvs[w][e][0];   // broadcast read
        const float p0 = exp2f(fmaf(a0, kv.x, -m0));
        const float p1 = exp2f(fmaf(a1, kv.x, -m1));
        s00 += p0;  s01 = fmaf(p0, kv.y, s01);
        s10 += p1;  s11 = fmaf(p1, kv.y, s11);
    }
    osm[w][lane]      = s01 / s00;
    osm[w][64 + lane] = s11 / s10;
    __syncthreads();

    float* orow = out + (size_t)token * (DH * NH);
#pragma unroll
    for (int it = 0; it < 16; ++it) {
        const int idx = it * 64 + lane;          // float4 index within the 4096-row
        const float val = osm[w][idx >> 3];      // d = (idx*4)/32
        float4 f4; f4.x = val; f4.y = val; f4.z = val; f4.w = val;
        *(float4*)(orow + idx * 4) = f4;
    }
}

// ---------------------------------------------------------------------------
extern "C" void kernel_launch(void* const* d_in, const int* in_sizes, int n_in,
                              void* d_out, int out_size, void* d_ws, size_t ws_size,
                              hipStream_t stream) {
    const float* x  = (const float*)d_in[0];
    const float* Wq = (const float*)d_in[1];
    const float* bq = (const float*)d_in[2];
    const float* Wk = (const float*)d_in[3];
    const float* bk = (const float*)d_in[4];
    const float* Wv = (const float*)d_in[5];
    const float* bv = (const float*)d_in[6];
    float* out = (float*)d_out;

    char* ws = (char*)d_ws;
    const size_t off_bias = 3145728;                 // W3F: 6*524288
    const size_t off_q0   = off_bias + 4096;
    const size_t off_q1   = off_q0 + (size_t)NTOK * NCOL * 4;
    const size_t need2    = off_q1 + (size_t)NTOK * NCOL * 4;  // 53,481,472 B

    unsigned short* W3F = (unsigned short*)ws;
    float* bias = (float*)(ws + off_bias);
    float* qkv0 = (float*)(ws + off_q0);
    const int nsplit = (ws_size >= need2) ? 2 : 1;
    float* qkv1 = (nsplit == 2) ? (float*)(ws + off_q1) : qkv0;

    prep_w<<<(NCOL * 512) / 256, 256, 0, stream>>>(Wq, bq, Wk, bk, Wv, bv, W3F, bias);
    gemm_qkv<<<256 * nsplit, 384, 0, stream>>>(x, W3F, qkv0, nsplit);
    attn_out<<<NTOK / 4, 256, 0, stream>>>(qkv0, qkv1, bias, out, nsplit);
}